// Round 4
// baseline (324.198 us; speedup 1.0000x reference)
//
#include <hip/hip_runtime.h>
#include <stdint.h>

// Problem constants (B=64, N=197)
#define M_TOK 12608      // 64*197 tokens
#define MPAD  12672      // 99 * 128
#define CIN   768
#define CD    256
#define NE    8192
#define NCHUNK 8
#define CHUNK  1024

typedef unsigned long long u64;
typedef unsigned int u32;
typedef _Float16 f16;
typedef _Float16 f16x8 __attribute__((ext_vector_type(8)));
typedef _Float16 f16x4 __attribute__((ext_vector_type(4)));
typedef float f32x4 __attribute__((ext_vector_type(4)));

#if __has_builtin(__builtin_amdgcn_global_load_lds)
#define HAVE_GLL 1
#else
#define HAVE_GLL 0
#endif

// Stage one 16B chunk per lane into LDS. lds_base is wave-uniform; HW (or the
// fallback) adds lane*16.
__device__ __forceinline__ void stage16(const f16* src, char* lds_base, int lane)
{
#if HAVE_GLL
    __builtin_amdgcn_global_load_lds(
        (__attribute__((address_space(1))) void*)(src),
        (__attribute__((address_space(3))) void*)(lds_base), 16, 0, 0);
#else
    *(f16x8*)(lds_base + lane * 16) = *(const f16x8*)src;
#endif
}

// ---------------------------------------------------------------------------
// Fused prep: region A (2048 blocks): enorm + embf16 + loss zero.
// Region B (768 blocks): weight prep (WcT hi/lo split, WeT f16).
// Region C (9456 blocks): z -> zhi + zlo split.
__global__ __launch_bounds__(256) void k_prep(const float* __restrict__ emb,
                                              const float* __restrict__ Wc,
                                              const float* __restrict__ We,
                                              const float* __restrict__ z,
                                              float* __restrict__ enorm,
                                              f16* __restrict__ embf16,
                                              f16* __restrict__ wchi,
                                              f16* __restrict__ wclo,
                                              f16* __restrict__ wet,
                                              f16* __restrict__ zhi,
                                              f16* __restrict__ zlo,
                                              float* __restrict__ loss_slot)
{
    const int b = blockIdx.x;
    const int t = threadIdx.x;
    if (b < 2048) {
        if (b == 0 && t == 0) *loss_slot = 0.0f;
        int row  = b * 4 + (t >> 6);
        int lane = t & 63;
        float4 v = *(const float4*)&emb[(size_t)row * CD + lane * 4];
        f16x4 hv = { (f16)v.x, (f16)v.y, (f16)v.z, (f16)v.w };
        *(f16x4*)&embf16[(size_t)row * CD + lane * 4] = hv;
        float s = v.x*v.x + v.y*v.y + v.z*v.z + v.w*v.w;
        #pragma unroll
        for (int o = 32; o; o >>= 1) s += __shfl_down(s, o, 64);
        if (lane == 0) enorm[row] = s;
    } else if (b < 2048 + 768) {
        int tid = (b - 2048) * 256 + t;            // < 196608
        {
            int n = tid & 255, k = tid >> 8;
            float v = Wc[(size_t)k * CD + n];
            f16 h = (f16)v;
            wchi[(size_t)n * CIN + k] = h;
            wclo[(size_t)n * CIN + k] = (f16)(v - (float)h);
        }
        {
            int d = tid / CIN, c = tid - d * CIN;
            wet[(size_t)c * CD + d] = (f16)We[(size_t)d * CIN + c];
        }
    } else {
        size_t i4 = (size_t)(b - 2816) * 256 + t;  // float4 idx, 2420736 total
        float4 v = ((const float4*)z)[i4];
        f16x4 h = { (f16)v.x, (f16)v.y, (f16)v.z, (f16)v.w };
        f16x4 lo = { (f16)(v.x - (float)h.x), (f16)(v.y - (float)h.y),
                     (f16)(v.z - (float)h.z), (f16)(v.w - (float)h.w) };
        ((f16x4*)zhi)[i4] = h;
        ((f16x4*)zlo)[i4] = lo;
    }
}

// ---------------------------------------------------------------------------
// Fused split-f16 compress: zc = zhi@WhiT + zhi@WloT + zlo@WhiT + bc (fp32-exact
// to ~2^-22), writes zc (f32) and zcf16 in the epilogue. 128x64 tile, BK=64,
// K=768. 4 waves, wave-tile 32x64 (2x4 of 16x16x32), 3 chained MFMA per pair.
__global__ __launch_bounds__(256) void k_compress_f(const f16* __restrict__ zhi,
                                                    const f16* __restrict__ zlo,
                                                    const f16* __restrict__ wchi,
                                                    const f16* __restrict__ wclo,
                                                    const float* __restrict__ bc,
                                                    float* __restrict__ zc,
                                                    f16* __restrict__ zcf16)
{
    __shared__ __align__(16) f16 Ah[128 * 64];   // 16 KB
    __shared__ __align__(16) f16 Al[128 * 64];   // 16 KB
    __shared__ __align__(16) f16 Bh[64 * 64];    // 8 KB
    __shared__ __align__(16) f16 Bl[64 * 64];    // 8 KB

    const int t = threadIdx.x;
    const int w = t >> 6, l = t & 63;
    const int wrow = w * 32;
    const int m0   = blockIdx.x * 128;
    const int col0 = blockIdx.y * 64;

    const int cg   = (t & 7) ^ ((t >> 3) & 7);
    const int rloc = t >> 3;
    const f16* ahsrc[4]; const f16* alsrc[4];
    #pragma unroll
    for (int i = 0; i < 4; ++i) {
        int am = m0 + i * 32 + rloc; am = am < M_TOK ? am : (M_TOK - 1);
        ahsrc[i] = zhi + (size_t)am * CIN + cg * 8;
        alsrc[i] = zlo + (size_t)am * CIN + cg * 8;
    }
    const f16* bhsrc[2]; const f16* blsrc[2];
    #pragma unroll
    for (int i = 0; i < 2; ++i) {
        int br = col0 + i * 32 + rloc;
        bhsrc[i] = wchi + (size_t)br * CIN + cg * 8;
        blsrc[i] = wclo + (size_t)br * CIN + cg * 8;
    }

    f32x4 acc[2][4];
    #pragma unroll
    for (int a = 0; a < 2; ++a)
        #pragma unroll
        for (int b2 = 0; b2 < 4; ++b2) acc[a][b2] = (f32x4){0.f,0.f,0.f,0.f};

    for (int ks = 0; ks < CIN / 64; ++ks) {
        __syncthreads();
        #pragma unroll
        for (int i = 0; i < 4; ++i) {
            stage16(ahsrc[i] + ks * 64, (char*)Ah + (i * 256 + w * 64) * 16, l);
            stage16(alsrc[i] + ks * 64, (char*)Al + (i * 256 + w * 64) * 16, l);
        }
        #pragma unroll
        for (int i = 0; i < 2; ++i) {
            stage16(bhsrc[i] + ks * 64, (char*)Bh + (i * 256 + w * 64) * 16, l);
            stage16(blsrc[i] + ks * 64, (char*)Bl + (i * 256 + w * 64) * 16, l);
        }
        __syncthreads();
        #pragma unroll
        for (int kk = 0; kk < 2; ++kk) {
            const int pofs = ((kk * 4 + (l >> 4)) ^ (l & 7)) * 16;
            f16x8 ah[2], al[2], bh[4], bl[4];
            #pragma unroll
            for (int tm = 0; tm < 2; ++tm) {
                ah[tm] = *(const f16x8*)((const char*)Ah + (wrow + tm*16 + (l & 15)) * 128 + pofs);
                al[tm] = *(const f16x8*)((const char*)Al + (wrow + tm*16 + (l & 15)) * 128 + pofs);
            }
            #pragma unroll
            for (int tn = 0; tn < 4; ++tn) {
                bh[tn] = *(const f16x8*)((const char*)Bh + (tn*16 + (l & 15)) * 128 + pofs);
                bl[tn] = *(const f16x8*)((const char*)Bl + (tn*16 + (l & 15)) * 128 + pofs);
            }
            #pragma unroll
            for (int tm = 0; tm < 2; ++tm)
                #pragma unroll
                for (int tn = 0; tn < 4; ++tn) {
                    f32x4 a = acc[tm][tn];
                    a = __builtin_amdgcn_mfma_f32_16x16x32_f16(ah[tm], bh[tn], a, 0, 0, 0);
                    a = __builtin_amdgcn_mfma_f32_16x16x32_f16(ah[tm], bl[tn], a, 0, 0, 0);
                    a = __builtin_amdgcn_mfma_f32_16x16x32_f16(al[tm], bh[tn], a, 0, 0, 0);
                    acc[tm][tn] = a;
                }
        }
    }

    #pragma unroll
    for (int tm = 0; tm < 2; ++tm) {
        #pragma unroll
        for (int reg = 0; reg < 4; ++reg) {
            int row = m0 + wrow + tm * 16 + (l >> 4) * 4 + reg;
            if (row < M_TOK) {
                #pragma unroll
                for (int tn = 0; tn < 4; ++tn) {
                    int col = col0 + tn * 16 + (l & 15);
                    float v = acc[tm][tn][reg] + bc[col];
                    zc[(size_t)row * CD + col] = v;
                    zcf16[(size_t)row * CD + col] = (f16)v;
                }
            }
        }
    }
}

// ---------------------------------------------------------------------------
// Coarse distance GEMM v2: block 128 rows x 256-col j-pass (4 passes/chunk),
// wave-tile 64x128 (acc[4][8]) -> 0.375 LDS reads/MFMA, 32 barriers/block.
__global__ __launch_bounds__(256, 2) void k_dist_mfma(const f16* __restrict__ zcf16,
                                                      const f16* __restrict__ embf16,
                                                      const float* __restrict__ enorm,
                                                      u64* __restrict__ part)
{
    __shared__ __align__(16) f16 As[128 * 64];   // 16 KB
    __shared__ __align__(16) f16 Bs[256 * 64];   // 32 KB
    __shared__ u64 wred[128][2][2];              // 2 KB

    const int t = threadIdx.x;
    const int w = t >> 6, l = t & 63;
    const int wrow  = (w >> 1) * 64;   // row-half
    const int wcolh = (w & 1);         // col-half (128 cols each)
    const int m0    = blockIdx.x * 128;
    const int chunk = blockIdx.y;

    const int cg   = (t & 7) ^ ((t >> 3) & 7);
    const int rloc = t >> 3;
    const f16* asrc[4];
    #pragma unroll
    for (int i = 0; i < 4; ++i) {
        int am = m0 + i * 32 + rloc; am = am < M_TOK ? am : (M_TOK - 1);
        asrc[i] = zcf16 + (size_t)am * CD + cg * 8;
    }

    float bd[16];
    int   bcol[16];
    #pragma unroll
    for (int s = 0; s < 16; ++s) { bd[s] = __builtin_inff(); bcol[s] = 0; }

    for (int jp = 0; jp < 4; ++jp) {
        const int j0 = chunk * CHUNK + jp * 256;
        const f16* bbase = embf16 + (size_t)(j0 + rloc) * CD + cg * 8;

        f32x4 acc[4][8];
        #pragma unroll
        for (int a = 0; a < 4; ++a)
            #pragma unroll
            for (int b2 = 0; b2 < 8; ++b2) acc[a][b2] = (f32x4){0.f,0.f,0.f,0.f};

        for (int ks = 0; ks < 4; ++ks) {        // K = 256
            __syncthreads();
            #pragma unroll
            for (int i = 0; i < 4; ++i)
                stage16(asrc[i] + ks * 64, (char*)As + (i * 256 + w * 64) * 16, l);
            #pragma unroll
            for (int i = 0; i < 8; ++i)
                stage16(bbase + (size_t)i * 32 * CD + ks * 64,
                        (char*)Bs + (i * 256 + w * 64) * 16, l);
            __syncthreads();
            #pragma unroll
            for (int kk = 0; kk < 2; ++kk) {
                const int pofs = ((kk * 4 + (l >> 4)) ^ (l & 7)) * 16;
                f16x8 af[4], bf[8];
                #pragma unroll
                for (int tm = 0; tm < 4; ++tm)
                    af[tm] = *(const f16x8*)((const char*)As + (wrow + tm*16 + (l & 15)) * 128 + pofs);
                #pragma unroll
                for (int tn = 0; tn < 8; ++tn)
                    bf[tn] = *(const f16x8*)((const char*)Bs + (wcolh*128 + tn*16 + (l & 15)) * 128 + pofs);
                #pragma unroll
                for (int tm = 0; tm < 4; ++tm)
                    #pragma unroll
                    for (int tn = 0; tn < 8; ++tn)
                        acc[tm][tn] = __builtin_amdgcn_mfma_f32_16x16x32_f16(af[tm], bf[tn], acc[tm][tn], 0, 0, 0);
            }
        }

        // epilogue: distances + per-lane running argmin per row-slot
        const int cb = j0 + wcolh * 128 + (l & 15);
        float en[8];
        #pragma unroll
        for (int tn = 0; tn < 8; ++tn) en[tn] = enorm[cb + tn * 16];
        #pragma unroll
        for (int tm = 0; tm < 4; ++tm) {
            #pragma unroll
            for (int reg = 0; reg < 4; ++reg) {
                const int s = tm * 4 + reg;
                float dm = bd[s]; int cm = bcol[s];
                #pragma unroll
                for (int tn = 0; tn < 8; ++tn) {
                    float d = fmaf(acc[tm][tn][reg], -2.f, en[tn]);
                    bool lt = d < dm;
                    dm = lt ? d : dm;
                    cm = lt ? cb + tn * 16 : cm;
                }
                bd[s] = dm; bcol[s] = cm;
            }
        }
    }

    // pack keys; top-2 across the 16 lanes sharing each row; merge halves in LDS
    #pragma unroll
    for (int tm = 0; tm < 4; ++tm) {
        #pragma unroll
        for (int reg = 0; reg < 4; ++reg) {
            const int s = tm * 4 + reg;
            u32 u = __float_as_uint(bd[s]);
            u = (u & 0x80000000u) ? ~u : (u | 0x80000000u);
            u64 b  = ((u64)u << 32) | (u32)bcol[s];
            u64 sc = ~0ull;
            #pragma unroll
            for (int off = 1; off <= 8; off <<= 1) {
                u64 ob = __shfl_xor(b, off, 64);
                u64 os = __shfl_xor(sc, off, 64);
                u64 nb = b < ob ? b : ob;
                u64 mx = b < ob ? ob : b;
                sc = sc < os ? sc : os;
                sc = sc < mx ? sc : mx;
                b = nb;
            }
            if ((l & 15) == 0) {
                int row = wrow + tm * 16 + (l >> 4) * 4 + reg;
                wred[row][w & 1][0] = b;
                wred[row][w & 1][1] = sc;
            }
        }
    }
    __syncthreads();
    if (t < 128) {
        u64 b0 = wred[t][0][0], s0 = wred[t][0][1];
        u64 b1 = wred[t][1][0], s1 = wred[t][1][1];
        u64 B  = b0 < b1 ? b0 : b1;
        u64 mx = b0 < b1 ? b1 : b0;
        u64 S  = s0 < s1 ? s0 : s1;
        S = S < mx ? S : mx;
        int row = m0 + t;
        if (row < M_TOK) {
            part[((size_t)row * NCHUNK + chunk) * 2 + 0] = B;
            part[((size_t)row * NCHUNK + chunk) * 2 + 1] = S;
        }
    }
}

// ---------------------------------------------------------------------------
// Exact fp32 rescore of 16 candidates/row -> final index; fused loss.
__global__ __launch_bounds__(256) void k_rescore(const float* __restrict__ zc,
                                                 const float* __restrict__ emb,
                                                 const float* __restrict__ enorm,
                                                 const u64* __restrict__ part,
                                                 int* __restrict__ idxp,
                                                 float* __restrict__ loss_slot)
{
    const int row = blockIdx.x * 4 + (threadIdx.x >> 6);   // grid 3152 -> exactly M_TOK
    const int l   = threadIdx.x & 63;
    __shared__ float lsum[4];

    float4 zr = *(const float4*)&zc[(size_t)row * CD + l * 4];
    u64 best = ~0ull;
    for (int c = 0; c < 16; ++c) {
        u64 key = part[(size_t)row * 16 + c];
        int col = (int)((u32)key & (NE - 1));
        float4 er = *(const float4*)&emb[(size_t)col * CD + l * 4];
        float p = zr.x*er.x + zr.y*er.y + zr.z*er.z + zr.w*er.w;
        #pragma unroll
        for (int o = 32; o; o >>= 1) p += __shfl_xor(p, o, 64);
        float d = fmaf(p, -2.f, enorm[col]);
        u32 u = __float_as_uint(d);
        u = (u & 0x80000000u) ? ~u : (u | 0x80000000u);
        u64 k2 = ((u64)u << 32) | (u32)col;
        best = k2 < best ? k2 : best;
    }
    float zn = zr.x*zr.x + zr.y*zr.y + zr.z*zr.z + zr.w*zr.w;
    #pragma unroll
    for (int o = 32; o; o >>= 1) zn += __shfl_xor(zn, o, 64);

    u32 hi = (u32)(best >> 32);
    float dbest = (hi & 0x80000000u) ? __uint_as_float(hi & 0x7fffffffu)
                                     : __uint_as_float(~hi);
    if (l == 0) {
        idxp[row] = (int)((u32)best & (NE - 1));
        lsum[threadIdx.x >> 6] = dbest + zn;
    }
    __syncthreads();
    if (threadIdx.x == 0) {
        float tot = lsum[0] + lsum[1] + lsum[2] + lsum[3];
        atomicAdd(loss_slot, tot * (3.0f / 3227648.0f));
    }
}

// ---------------------------------------------------------------------------
// Expand GEMM (f16 MFMA, gathered A): out = embf16[idx] @ WeT^T + be. 128x128, K=256.
__global__ __launch_bounds__(256) void k_expand_mfma(const f16* __restrict__ embf16,
                                                     const int* __restrict__ idxp,
                                                     const f16* __restrict__ wet,
                                                     const float* __restrict__ be,
                                                     float* __restrict__ out)
{
    __shared__ __align__(16) f16 As[128 * 64];
    __shared__ __align__(16) f16 Bs[128 * 64];

    const int t = threadIdx.x;
    const int w = t >> 6, l = t & 63;
    const int wrow = (w >> 1) * 64, wcol = (w & 1) * 64;
    const int m0   = blockIdx.x * 128;
    const int col0 = blockIdx.y * 128;

    const int cg   = (t & 7) ^ ((t >> 3) & 7);
    const int rloc = t >> 3;
    const f16* asrc[4]; const f16* bsrc[4];
    #pragma unroll
    for (int i = 0; i < 4; ++i) {
        int r = i * 32 + rloc;
        int m = m0 + r; m = m < M_TOK ? m : (M_TOK - 1);
        int er = idxp[m];
        asrc[i] = embf16 + (size_t)er * CD + cg * 8;
        bsrc[i] = wet + (size_t)(col0 + r) * CD + cg * 8;
    }
    const int prd0 = (l >> 4) ^ (l & 7);
    const int prd1 = (4 + (l >> 4)) ^ (l & 7);

    f32x4 acc[4][4];
    #pragma unroll
    for (int a = 0; a < 4; ++a)
        #pragma unroll
        for (int b = 0; b < 4; ++b) acc[a][b] = (f32x4){0.f,0.f,0.f,0.f};

    for (int ks = 0; ks < 4; ++ks) {            // K = 256
        __syncthreads();
        #pragma unroll
        for (int i = 0; i < 4; ++i) {
            stage16(asrc[i] + ks * 64, (char*)As + (i * 256 + w * 64) * 16, l);
            stage16(bsrc[i] + ks * 64, (char*)Bs + (i * 256 + w * 64) * 16, l);
        }
        __syncthreads();
        #pragma unroll
        for (int kk = 0; kk < 2; ++kk) {
            const int pofs = (kk ? prd1 : prd0) * 16;
            f16x8 af[4], bf[4];
            #pragma unroll
            for (int tm = 0; tm < 4; ++tm)
                af[tm] = *(const f16x8*)((const char*)As + (wrow + tm*16 + (l & 15)) * 128 + pofs);
            #pragma unroll
            for (int tn = 0; tn < 4; ++tn)
                bf[tn] = *(const f16x8*)((const char*)Bs + (wcol + tn*16 + (l & 15)) * 128 + pofs);
            #pragma unroll
            for (int tm = 0; tm < 4; ++tm)
                #pragma unroll
                for (int tn = 0; tn < 4; ++tn)
                    acc[tm][tn] = __builtin_amdgcn_mfma_f32_16x16x32_f16(af[tm], bf[tn], acc[tm][tn], 0, 0, 0);
        }
    }

    float bev[4];
    #pragma unroll
    for (int tn = 0; tn < 4; ++tn) bev[tn] = be[col0 + wcol + tn * 16 + (l & 15)];
    #pragma unroll
    for (int tm = 0; tm < 4; ++tm) {
        #pragma unroll
        for (int reg = 0; reg < 4; ++reg) {
            int row = m0 + wrow + tm * 16 + (l >> 4) * 4 + reg;
            if (row < M_TOK) {
                #pragma unroll
                for (int tn = 0; tn < 4; ++tn) {
                    int col = col0 + wcol + tn * 16 + (l & 15);
                    out[(size_t)row * CIN + col] = acc[tm][tn][reg] + bev[tn];
                }
            }
        }
    }
}

// ---------------------------------------------------------------------------
// fp32 fallback compress (only if workspace too small for the split path)
#define BK1 16
__global__ __launch_bounds__(256) void k_compress(const float* __restrict__ z,
                                                  const float* __restrict__ W,
                                                  const float* __restrict__ bias,
                                                  float* __restrict__ zc,
                                                  f16* __restrict__ zcf16)
{
    __shared__ __align__(16) float As[BK1][64 + 4];
    __shared__ __align__(16) float Bs[BK1][64 + 4];
    const int t  = threadIdx.x;
    const int tx = t & 15, ty = t >> 4;
    const int row0 = blockIdx.x * 64;
    const int col0 = blockIdx.y * 64;

    const int la_r = t >> 2;
    const int la_k = (t & 3) << 2;
    const int lb_k = t >> 4;
    const int lb_n = (t & 15) << 2;

    float acc[4][4] = {};

    for (int k0 = 0; k0 < CIN; k0 += BK1) {
        float4 a4 = *(const float4*)&z[(size_t)(row0 + la_r) * CIN + k0 + la_k];
        float4 b4 = *(const float4*)&W[(size_t)(k0 + lb_k) * CD + col0 + lb_n];
        __syncthreads();
        As[la_k + 0][la_r] = a4.x; As[la_k + 1][la_r] = a4.y;
        As[la_k + 2][la_r] = a4.z; As[la_k + 3][la_r] = a4.w;
        *(float4*)&Bs[lb_k][lb_n] = b4;
        __syncthreads();
        #pragma unroll
        for (int k = 0; k < BK1; ++k) {
            float a[4], b[4];
            *(float4*)&a[0] = *(const float4*)&As[k][ty * 4];
            *(float4*)&b[0] = *(const float4*)&Bs[k][tx * 4];
            #pragma unroll
            for (int i = 0; i < 4; ++i)
                #pragma unroll
                for (int j = 0; j < 4; ++j)
                    acc[i][j] = fmaf(a[i], b[j], acc[i][j]);
        }
    }

    float4 bb = *(const float4*)&bias[col0 + tx * 4];
    #pragma unroll
    for (int i = 0; i < 4; ++i) {
        float4 v;
        v.x = acc[i][0] + bb.x; v.y = acc[i][1] + bb.y;
        v.z = acc[i][2] + bb.z; v.w = acc[i][3] + bb.w;
        size_t off = (size_t)(row0 + ty * 4 + i) * CD + col0 + tx * 4;
        *(float4*)&zc[off] = v;
        f16x4 hv = { (f16)v.x, (f16)v.y, (f16)v.z, (f16)v.w };
        *(f16x4*)&zcf16[off] = hv;
    }
}

// ---------------------------------------------------------------------------
extern "C" void kernel_launch(void* const* d_in, const int* in_sizes, int n_in,
                              void* d_out, int out_size, void* d_ws, size_t ws_size,
                              hipStream_t stream)
{
    (void)in_sizes; (void)n_in; (void)out_size;

    const float* z   = (const float*)d_in[0];
    const float* emb = (const float*)d_in[1];
    const float* Wc  = (const float*)d_in[2];
    const float* bc  = (const float*)d_in[3];
    const float* We  = (const float*)d_in[4];
    const float* be  = (const float*)d_in[5];

    float* out       = (float*)d_out;
    float* loss_slot = out + (size_t)M_TOK * CIN;

    char* base = (char*)d_ws;
    size_t off = 0;
    auto align_up = [](size_t x) { return (x + 255) & ~(size_t)255; };

    float* enorm = (float*)(base + off); off = align_up(off + (size_t)NE * 4);
    u64*   part  = (u64*)(base + off);   off = align_up(off + (size_t)M_TOK * 16 * 8);
    int*   idxp  = (int*)(base + off);   off = align_up(off + (size_t)M_TOK * 4);
    f16*   embf16= (f16*)(base + off);   off = align_up(off + (size_t)NE * CD * 2);
    f16*   zcf16 = (f16*)(base + off);   off = align_up(off + (size_t)MPAD * CD * 2);
    f16*   wet   = (f16*)(base + off);   off = align_up(off + (size_t)CIN * CD * 2);
    f16*   wchi  = (f16*)(base + off);   off = align_up(off + (size_t)CD * CIN * 2);
    f16*   wclo  = (f16*)(base + off);   off = align_up(off + (size_t)CD * CIN * 2);

    const size_t zsplit_bytes = (size_t)M_TOK * CIN * 2;
    bool have_split = (ws_size >= off + 2 * zsplit_bytes);
    f16 *zhi = nullptr, *zlo = nullptr;
    if (have_split) {
        zhi = (f16*)(base + off); off = align_up(off + zsplit_bytes);
        zlo = (f16*)(base + off); off = align_up(off + zsplit_bytes);
    }
    const size_t zc_bytes = (size_t)M_TOK * CD * 4;
    float* zc = (ws_size >= off + zc_bytes) ? (float*)(base + off) : out;

    if (have_split) {
        k_prep      <<<12272, 256, 0, stream>>>(emb, Wc, We, z, enorm, embf16,
                                                wchi, wclo, wet, zhi, zlo, loss_slot);
        k_compress_f<<<dim3(MPAD / 128, CD / 64), 256, 0, stream>>>(zhi, zlo, wchi, wclo,
                                                                    bc, zc, zcf16);
    } else {
        k_prep    <<<2816, 256, 0, stream>>>(emb, Wc, We, z, enorm, embf16,
                                             wchi, wclo, wet, (f16*)wchi, (f16*)wclo, loss_slot);
        k_compress<<<dim3(M_TOK / 64, CD / 64), 256, 0, stream>>>(z, Wc, bc, zc, zcf16);
    }

    k_dist_mfma  <<<dim3(MPAD / 128, NCHUNK), 256, 0, stream>>>(zcf16, embf16, enorm, part);
    k_rescore    <<<M_TOK / 4, 256, 0, stream>>>(zc, emb, enorm, part, idxp, loss_slot);
    k_expand_mfma<<<dim3(MPAD / 128, CIN / 128), 256, 0, stream>>>(embf16, idxp, wet, be, out);
}

// Round 5
// 285.160 us; speedup vs baseline: 1.1369x; 1.1369x over previous
//
#include <hip/hip_runtime.h>
#include <stdint.h>

// Problem constants (B=64, N=197)
#define M_TOK 12608      // 64*197 tokens
#define MPAD  12672      // 99 * 128
#define CIN   768
#define CD    256
#define NE    8192
#define NCHUNK 8
#define CHUNK  1024

typedef unsigned long long u64;
typedef unsigned int u32;
typedef _Float16 f16;
typedef _Float16 f16x8 __attribute__((ext_vector_type(8)));
typedef _Float16 f16x4 __attribute__((ext_vector_type(4)));
typedef float f32x4 __attribute__((ext_vector_type(4)));

#if __has_builtin(__builtin_amdgcn_global_load_lds)
#define HAVE_GLL 1
#else
#define HAVE_GLL 0
#endif

// Stage one 16B chunk per lane into LDS. lds_base is wave-uniform; HW (or the
// fallback) adds lane*16.
__device__ __forceinline__ void stage16(const f16* src, char* lds_base, int lane)
{
#if HAVE_GLL
    __builtin_amdgcn_global_load_lds(
        (__attribute__((address_space(1))) void*)(src),
        (__attribute__((address_space(3))) void*)(lds_base), 16, 0, 0);
#else
    *(f16x8*)(lds_base + lane * 16) = *(const f16x8*)src;
#endif
}

// ---------------------------------------------------------------------------
// Fused prep: region A (2048 blocks): enorm + embf16 + loss zero.
// Region B (768 blocks): weight prep (WcT hi/lo split, WeT f16).
// Region C (9456 blocks): z -> zhi + zlo split.
__global__ __launch_bounds__(256) void k_prep(const float* __restrict__ emb,
                                              const float* __restrict__ Wc,
                                              const float* __restrict__ We,
                                              const float* __restrict__ z,
                                              float* __restrict__ enorm,
                                              f16* __restrict__ embf16,
                                              f16* __restrict__ wchi,
                                              f16* __restrict__ wclo,
                                              f16* __restrict__ wet,
                                              f16* __restrict__ zhi,
                                              f16* __restrict__ zlo,
                                              float* __restrict__ loss_slot)
{
    const int b = blockIdx.x;
    const int t = threadIdx.x;
    if (b < 2048) {
        if (b == 0 && t == 0) *loss_slot = 0.0f;
        int row  = b * 4 + (t >> 6);
        int lane = t & 63;
        float4 v = *(const float4*)&emb[(size_t)row * CD + lane * 4];
        f16x4 hv = { (f16)v.x, (f16)v.y, (f16)v.z, (f16)v.w };
        *(f16x4*)&embf16[(size_t)row * CD + lane * 4] = hv;
        float s = v.x*v.x + v.y*v.y + v.z*v.z + v.w*v.w;
        #pragma unroll
        for (int o = 32; o; o >>= 1) s += __shfl_down(s, o, 64);
        if (lane == 0) enorm[row] = s;
    } else if (b < 2048 + 768) {
        int tid = (b - 2048) * 256 + t;            // < 196608
        {
            int n = tid & 255, k = tid >> 8;
            float v = Wc[(size_t)k * CD + n];
            f16 h = (f16)v;
            wchi[(size_t)n * CIN + k] = h;
            wclo[(size_t)n * CIN + k] = (f16)(v - (float)h);
        }
        {
            int d = tid / CIN, c = tid - d * CIN;
            wet[(size_t)c * CD + d] = (f16)We[(size_t)d * CIN + c];
        }
    } else {
        size_t i4 = (size_t)(b - 2816) * 256 + t;  // float4 idx, 2420736 total
        float4 v = ((const float4*)z)[i4];
        f16x4 h = { (f16)v.x, (f16)v.y, (f16)v.z, (f16)v.w };
        f16x4 lo = { (f16)(v.x - (float)h.x), (f16)(v.y - (float)h.y),
                     (f16)(v.z - (float)h.z), (f16)(v.w - (float)h.w) };
        ((f16x4*)zhi)[i4] = h;
        ((f16x4*)zlo)[i4] = lo;
    }
}

// ---------------------------------------------------------------------------
// Fused split-f16 compress: zc = zhi@WhiT + zhi@WloT + zlo@WhiT + bc, writes
// zc (f32) and zcf16. 128x64 tile, BK=64, K=768.
__global__ __launch_bounds__(256) void k_compress_f(const f16* __restrict__ zhi,
                                                    const f16* __restrict__ zlo,
                                                    const f16* __restrict__ wchi,
                                                    const f16* __restrict__ wclo,
                                                    const float* __restrict__ bc,
                                                    float* __restrict__ zc,
                                                    f16* __restrict__ zcf16)
{
    __shared__ __align__(16) f16 Ah[128 * 64];   // 16 KB
    __shared__ __align__(16) f16 Al[128 * 64];   // 16 KB
    __shared__ __align__(16) f16 Bh[64 * 64];    // 8 KB
    __shared__ __align__(16) f16 Bl[64 * 64];    // 8 KB

    const int t = threadIdx.x;
    const int w = t >> 6, l = t & 63;
    const int wrow = w * 32;
    const int m0   = blockIdx.x * 128;
    const int col0 = blockIdx.y * 64;

    const int cg   = (t & 7) ^ ((t >> 3) & 7);
    const int rloc = t >> 3;
    const f16* ahsrc[4]; const f16* alsrc[4];
    #pragma unroll
    for (int i = 0; i < 4; ++i) {
        int am = m0 + i * 32 + rloc; am = am < M_TOK ? am : (M_TOK - 1);
        ahsrc[i] = zhi + (size_t)am * CIN + cg * 8;
        alsrc[i] = zlo + (size_t)am * CIN + cg * 8;
    }
    const f16* bhsrc[2]; const f16* blsrc[2];
    #pragma unroll
    for (int i = 0; i < 2; ++i) {
        int br = col0 + i * 32 + rloc;
        bhsrc[i] = wchi + (size_t)br * CIN + cg * 8;
        blsrc[i] = wclo + (size_t)br * CIN + cg * 8;
    }

    f32x4 acc[2][4];
    #pragma unroll
    for (int a = 0; a < 2; ++a)
        #pragma unroll
        for (int b2 = 0; b2 < 4; ++b2) acc[a][b2] = (f32x4){0.f,0.f,0.f,0.f};

    for (int ks = 0; ks < CIN / 64; ++ks) {
        __syncthreads();
        #pragma unroll
        for (int i = 0; i < 4; ++i) {
            stage16(ahsrc[i] + ks * 64, (char*)Ah + (i * 256 + w * 64) * 16, l);
            stage16(alsrc[i] + ks * 64, (char*)Al + (i * 256 + w * 64) * 16, l);
        }
        #pragma unroll
        for (int i = 0; i < 2; ++i) {
            stage16(bhsrc[i] + ks * 64, (char*)Bh + (i * 256 + w * 64) * 16, l);
            stage16(blsrc[i] + ks * 64, (char*)Bl + (i * 256 + w * 64) * 16, l);
        }
        __syncthreads();
        #pragma unroll
        for (int kk = 0; kk < 2; ++kk) {
            const int pofs = ((kk * 4 + (l >> 4)) ^ (l & 7)) * 16;
            f16x8 ah[2], al[2], bh[4], bl[4];
            #pragma unroll
            for (int tm = 0; tm < 2; ++tm) {
                ah[tm] = *(const f16x8*)((const char*)Ah + (wrow + tm*16 + (l & 15)) * 128 + pofs);
                al[tm] = *(const f16x8*)((const char*)Al + (wrow + tm*16 + (l & 15)) * 128 + pofs);
            }
            #pragma unroll
            for (int tn = 0; tn < 4; ++tn) {
                bh[tn] = *(const f16x8*)((const char*)Bh + (tn*16 + (l & 15)) * 128 + pofs);
                bl[tn] = *(const f16x8*)((const char*)Bl + (tn*16 + (l & 15)) * 128 + pofs);
            }
            #pragma unroll
            for (int tm = 0; tm < 2; ++tm)
                #pragma unroll
                for (int tn = 0; tn < 4; ++tn) {
                    f32x4 a = acc[tm][tn];
                    a = __builtin_amdgcn_mfma_f32_16x16x32_f16(ah[tm], bh[tn], a, 0, 0, 0);
                    a = __builtin_amdgcn_mfma_f32_16x16x32_f16(ah[tm], bl[tn], a, 0, 0, 0);
                    a = __builtin_amdgcn_mfma_f32_16x16x32_f16(al[tm], bh[tn], a, 0, 0, 0);
                    acc[tm][tn] = a;
                }
        }
    }

    #pragma unroll
    for (int tm = 0; tm < 2; ++tm) {
        #pragma unroll
        for (int reg = 0; reg < 4; ++reg) {
            int row = m0 + wrow + tm * 16 + (l >> 4) * 4 + reg;
            if (row < M_TOK) {
                #pragma unroll
                for (int tn = 0; tn < 4; ++tn) {
                    int col = col0 + tn * 16 + (l & 15);
                    float v = acc[tm][tn][reg] + bc[col];
                    zc[(size_t)row * CD + col] = v;
                    zcf16[(size_t)row * CD + col] = (f16)v;
                }
            }
        }
    }
}

// ---------------------------------------------------------------------------
// Coarse distance GEMM v3: A (zc) held entirely in VGPRs (64 rows x 256 K per
// wave = 128 VGPRs of f16x8 frags, loaded once per block), LDS carries only B
// (32 KB per 64-col j-tile, XOR-swizzled). Per k-step: 1 ds_read feeds 4 MFMAs.
// Running per-slot argmin packs the 4-bit tile index into the distance's low
// mantissa bits (<=16 ulp perturbation; exact rescore fixes any flip).
__global__ __launch_bounds__(256, 2) void k_dist_mfma(const f16* __restrict__ zcf16,
                                                      const f16* __restrict__ embf16,
                                                      const float* __restrict__ enorm,
                                                      u64* __restrict__ part)
{
    __shared__ __align__(16) f16 Bs[64 * 256];   // 32 KB, swizzled
    __shared__ u64 wred[128][2][2];              // 2 KB

    const int t = threadIdx.x;
    const int w = t >> 6, l = t & 63;
    const int rg  = w >> 1;          // row-group (64 rows each)
    const int cgp = w & 1;           // col-group (32 of 64 cols per tile)
    const int m0    = blockIdx.x * 128;
    const int chunk = blockIdx.y;
    const int jbase = chunk * CHUNK;

    // ---- A fragments: 64 rows x 256 K in registers (coalesced 16-row x 64B)
    f16x8 afr[4][8];
    {
        const int rbase = m0 + rg * 64 + (l & 15);
        #pragma unroll
        for (int mb = 0; mb < 4; ++mb) {
            int r = rbase + mb * 16; r = r < M_TOK ? r : (M_TOK - 1);
            const f16* p = zcf16 + (size_t)r * CD + (l >> 4) * 8;
            #pragma unroll
            for (int ks = 0; ks < 8; ++ks)
                afr[mb][ks] = *(const f16x8*)(p + ks * 32);
        }
    }

    float bd[2][16];
    #pragma unroll
    for (int sc = 0; sc < 2; ++sc)
        #pragma unroll
        for (int s = 0; s < 16; ++s) bd[sc][s] = __builtin_inff();

    for (int jt = 0; jt < 16; ++jt) {
        const int j0 = jbase + jt * 64;
        __syncthreads();
        // stage B tile: 64 cols x 256 K, chunk c of col r stored at slot c^(r&7)
        #pragma unroll
        for (int i = 0; i < 8; ++i) {
            int r = (w * 8 + i) * 2 + (l >> 5);
            int c = (l & 31) ^ (r & 7);
            stage16(embf16 + (size_t)(j0 + r) * CD + c * 8,
                    (char*)Bs + (w * 8 + i) * 1024, l);
        }
        __syncthreads();

        #pragma unroll
        for (int sc = 0; sc < 2; ++sc) {
            const int colrow = cgp * 32 + sc * 16 + (l & 15);
            f32x4 acc[4];
            #pragma unroll
            for (int mb = 0; mb < 4; ++mb) acc[mb] = (f32x4){0.f,0.f,0.f,0.f};
            #pragma unroll
            for (int ks = 0; ks < 8; ++ks) {
                int pc = (ks * 4 + (l >> 4)) ^ (colrow & 7);
                f16x8 bf = *(const f16x8*)((const char*)Bs + colrow * 512 + pc * 16);
                #pragma unroll
                for (int mb = 0; mb < 4; ++mb)
                    acc[mb] = __builtin_amdgcn_mfma_f32_16x16x32_f16(afr[mb][ks], bf, acc[mb], 0, 0, 0);
            }
            float en = enorm[j0 + colrow];
            #pragma unroll
            for (int mb = 0; mb < 4; ++mb) {
                #pragma unroll
                for (int reg = 0; reg < 4; ++reg) {
                    float d = fmaf(acc[mb][reg], -2.f, en);
                    float ds = __uint_as_float((__float_as_uint(d) & ~15u) | (u32)jt);
                    float cur = bd[sc][mb * 4 + reg];
                    bd[sc][mb * 4 + reg] = ds < cur ? ds : cur;
                }
            }
        }
    }

    // ---- per-row top-2 across the 16 col-lanes, then merge col-groups in LDS
    #pragma unroll
    for (int mb = 0; mb < 4; ++mb) {
        #pragma unroll
        for (int reg = 0; reg < 4; ++reg) {
            u64 key[2];
            #pragma unroll
            for (int sc = 0; sc < 2; ++sc) {
                u32 bits = __float_as_uint(bd[sc][mb * 4 + reg]);
                int jtb  = (int)(bits & 15u);
                int col  = jbase + jtb * 64 + cgp * 32 + sc * 16 + (l & 15);
                u32 u = (bits & 0x80000000u) ? ~bits : (bits | 0x80000000u);
                key[sc] = ((u64)u << 32) | (u32)col;
            }
            u64 b  = key[0] < key[1] ? key[0] : key[1];
            u64 s2 = key[0] < key[1] ? key[1] : key[0];
            #pragma unroll
            for (int off = 1; off <= 8; off <<= 1) {
                u64 ob = __shfl_xor(b, off, 64);
                u64 os = __shfl_xor(s2, off, 64);
                u64 nb = b < ob ? b : ob;
                u64 mx = b < ob ? ob : b;
                s2 = s2 < os ? s2 : os;
                s2 = s2 < mx ? s2 : mx;
                b = nb;
            }
            if ((l & 15) == 0) {
                int row = rg * 64 + mb * 16 + (l >> 4) * 4 + reg;
                wred[row][cgp][0] = b;
                wred[row][cgp][1] = s2;
            }
        }
    }
    __syncthreads();
    if (t < 128) {
        u64 b0 = wred[t][0][0], s0 = wred[t][0][1];
        u64 b1 = wred[t][1][0], s1 = wred[t][1][1];
        u64 B  = b0 < b1 ? b0 : b1;
        u64 mx = b0 < b1 ? b1 : b0;
        u64 S  = s0 < s1 ? s0 : s1;
        S = S < mx ? S : mx;
        int row = m0 + t;
        if (row < M_TOK) {
            part[((size_t)row * NCHUNK + chunk) * 2 + 0] = B;
            part[((size_t)row * NCHUNK + chunk) * 2 + 1] = S;
        }
    }
}

// ---------------------------------------------------------------------------
// Exact fp32 rescore of 16 candidates/row -> final index; fused loss.
__global__ __launch_bounds__(256) void k_rescore(const float* __restrict__ zc,
                                                 const float* __restrict__ emb,
                                                 const float* __restrict__ enorm,
                                                 const u64* __restrict__ part,
                                                 int* __restrict__ idxp,
                                                 float* __restrict__ loss_slot)
{
    const int row = blockIdx.x * 4 + (threadIdx.x >> 6);   // grid 3152 -> exactly M_TOK
    const int l   = threadIdx.x & 63;
    __shared__ float lsum[4];

    float4 zr = *(const float4*)&zc[(size_t)row * CD + l * 4];
    u64 best = ~0ull;
    for (int c = 0; c < 16; ++c) {
        u64 key = part[(size_t)row * 16 + c];
        int col = (int)((u32)key & (NE - 1));
        float4 er = *(const float4*)&emb[(size_t)col * CD + l * 4];
        float p = zr.x*er.x + zr.y*er.y + zr.z*er.z + zr.w*er.w;
        #pragma unroll
        for (int o = 32; o; o >>= 1) p += __shfl_xor(p, o, 64);
        float d = fmaf(p, -2.f, enorm[col]);
        u32 u = __float_as_uint(d);
        u = (u & 0x80000000u) ? ~u : (u | 0x80000000u);
        u64 k2 = ((u64)u << 32) | (u32)col;
        best = k2 < best ? k2 : best;
    }
    float zn = zr.x*zr.x + zr.y*zr.y + zr.z*zr.z + zr.w*zr.w;
    #pragma unroll
    for (int o = 32; o; o >>= 1) zn += __shfl_xor(zn, o, 64);

    u32 hi = (u32)(best >> 32);
    float dbest = (hi & 0x80000000u) ? __uint_as_float(hi & 0x7fffffffu)
                                     : __uint_as_float(~hi);
    if (l == 0) {
        idxp[row] = (int)((u32)best & (NE - 1));
        lsum[threadIdx.x >> 6] = dbest + zn;
    }
    __syncthreads();
    if (threadIdx.x == 0) {
        float tot = lsum[0] + lsum[1] + lsum[2] + lsum[3];
        atomicAdd(loss_slot, tot * (3.0f / 3227648.0f));
    }
}

// ---------------------------------------------------------------------------
// Expand GEMM (f16 MFMA, gathered A): out = embf16[idx] @ WeT^T + be. 128x128, K=256.
__global__ __launch_bounds__(256) void k_expand_mfma(const f16* __restrict__ embf16,
                                                     const int* __restrict__ idxp,
                                                     const f16* __restrict__ wet,
                                                     const float* __restrict__ be,
                                                     float* __restrict__ out)
{
    __shared__ __align__(16) f16 As[128 * 64];
    __shared__ __align__(16) f16 Bs[128 * 64];

    const int t = threadIdx.x;
    const int w = t >> 6, l = t & 63;
    const int wrow = (w >> 1) * 64, wcol = (w & 1) * 64;
    const int m0   = blockIdx.x * 128;
    const int col0 = blockIdx.y * 128;

    const int cg   = (t & 7) ^ ((t >> 3) & 7);
    const int rloc = t >> 3;
    const f16* asrc[4]; const f16* bsrc[4];
    #pragma unroll
    for (int i = 0; i < 4; ++i) {
        int r = i * 32 + rloc;
        int m = m0 + r; m = m < M_TOK ? m : (M_TOK - 1);
        int er = idxp[m];
        asrc[i] = embf16 + (size_t)er * CD + cg * 8;
        bsrc[i] = wet + (size_t)(col0 + r) * CD + cg * 8;
    }
    const int prd0 = (l >> 4) ^ (l & 7);
    const int prd1 = (4 + (l >> 4)) ^ (l & 7);

    f32x4 acc[4][4];
    #pragma unroll
    for (int a = 0; a < 4; ++a)
        #pragma unroll
        for (int b = 0; b < 4; ++b) acc[a][b] = (f32x4){0.f,0.f,0.f,0.f};

    for (int ks = 0; ks < 4; ++ks) {            // K = 256
        __syncthreads();
        #pragma unroll
        for (int i = 0; i < 4; ++i) {
            stage16(asrc[i] + ks * 64, (char*)As + (i * 256 + w * 64) * 16, l);
            stage16(bsrc[i] + ks * 64, (char*)Bs + (i * 256 + w * 64) * 16, l);
        }
        __syncthreads();
        #pragma unroll
        for (int kk = 0; kk < 2; ++kk) {
            const int pofs = (kk ? prd1 : prd0) * 16;
            f16x8 af[4], bf[4];
            #pragma unroll
            for (int tm = 0; tm < 4; ++tm)
                af[tm] = *(const f16x8*)((const char*)As + (wrow + tm*16 + (l & 15)) * 128 + pofs);
            #pragma unroll
            for (int tn = 0; tn < 4; ++tn)
                bf[tn] = *(const f16x8*)((const char*)Bs + (wcol + tn*16 + (l & 15)) * 128 + pofs);
            #pragma unroll
            for (int tm = 0; tm < 4; ++tm)
                #pragma unroll
                for (int tn = 0; tn < 4; ++tn)
                    acc[tm][tn] = __builtin_amdgcn_mfma_f32_16x16x32_f16(af[tm], bf[tn], acc[tm][tn], 0, 0, 0);
        }
    }

    float bev[4];
    #pragma unroll
    for (int tn = 0; tn < 4; ++tn) bev[tn] = be[col0 + wcol + tn * 16 + (l & 15)];
    #pragma unroll
    for (int tm = 0; tm < 4; ++tm) {
        #pragma unroll
        for (int reg = 0; reg < 4; ++reg) {
            int row = m0 + wrow + tm * 16 + (l >> 4) * 4 + reg;
            if (row < M_TOK) {
                #pragma unroll
                for (int tn = 0; tn < 4; ++tn) {
                    int col = col0 + wcol + tn * 16 + (l & 15);
                    out[(size_t)row * CIN + col] = acc[tm][tn][reg] + bev[tn];
                }
            }
        }
    }
}

// ---------------------------------------------------------------------------
// fp32 fallback compress (only if workspace too small for the split path)
#define BK1 16
__global__ __launch_bounds__(256) void k_compress(const float* __restrict__ z,
                                                  const float* __restrict__ W,
                                                  const float* __restrict__ bias,
                                                  float* __restrict__ zc,
                                                  f16* __restrict__ zcf16)
{
    __shared__ __align__(16) float As[BK1][64 + 4];
    __shared__ __align__(16) float Bs[BK1][64 + 4];
    const int t  = threadIdx.x;
    const int tx = t & 15, ty = t >> 4;
    const int row0 = blockIdx.x * 64;
    const int col0 = blockIdx.y * 64;

    const int la_r = t >> 2;
    const int la_k = (t & 3) << 2;
    const int lb_k = t >> 4;
    const int lb_n = (t & 15) << 2;

    float acc[4][4] = {};

    for (int k0 = 0; k0 < CIN; k0 += BK1) {
        float4 a4 = *(const float4*)&z[(size_t)(row0 + la_r) * CIN + k0 + la_k];
        float4 b4 = *(const float4*)&W[(size_t)(k0 + lb_k) * CD + col0 + lb_n];
        __syncthreads();
        As[la_k + 0][la_r] = a4.x; As[la_k + 1][la_r] = a4.y;
        As[la_k + 2][la_r] = a4.z; As[la_k + 3][la_r] = a4.w;
        *(float4*)&Bs[lb_k][lb_n] = b4;
        __syncthreads();
        #pragma unroll
        for (int k = 0; k < BK1; ++k) {
            float a[4], b[4];
            *(float4*)&a[0] = *(const float4*)&As[k][ty * 4];
            *(float4*)&b[0] = *(const float4*)&Bs[k][tx * 4];
            #pragma unroll
            for (int i = 0; i < 4; ++i)
                #pragma unroll
                for (int j = 0; j < 4; ++j)
                    acc[i][j] = fmaf(a[i], b[j], acc[i][j]);
        }
    }

    float4 bb = *(const float4*)&bias[col0 + tx * 4];
    #pragma unroll
    for (int i = 0; i < 4; ++i) {
        float4 v;
        v.x = acc[i][0] + bb.x; v.y = acc[i][1] + bb.y;
        v.z = acc[i][2] + bb.z; v.w = acc[i][3] + bb.w;
        size_t off = (size_t)(row0 + ty * 4 + i) * CD + col0 + tx * 4;
        *(float4*)&zc[off] = v;
        f16x4 hv = { (f16)v.x, (f16)v.y, (f16)v.z, (f16)v.w };
        *(f16x4*)&zcf16[off] = hv;
    }
}

// ---------------------------------------------------------------------------
extern "C" void kernel_launch(void* const* d_in, const int* in_sizes, int n_in,
                              void* d_out, int out_size, void* d_ws, size_t ws_size,
                              hipStream_t stream)
{
    (void)in_sizes; (void)n_in; (void)out_size;

    const float* z   = (const float*)d_in[0];
    const float* emb = (const float*)d_in[1];
    const float* Wc  = (const float*)d_in[2];
    const float* bc  = (const float*)d_in[3];
    const float* We  = (const float*)d_in[4];
    const float* be  = (const float*)d_in[5];

    float* out       = (float*)d_out;
    float* loss_slot = out + (size_t)M_TOK * CIN;

    char* base = (char*)d_ws;
    size_t off = 0;
    auto align_up = [](size_t x) { return (x + 255) & ~(size_t)255; };

    float* enorm = (float*)(base + off); off = align_up(off + (size_t)NE * 4);
    u64*   part  = (u64*)(base + off);   off = align_up(off + (size_t)M_TOK * 16 * 8);
    int*   idxp  = (int*)(base + off);   off = align_up(off + (size_t)M_TOK * 4);
    f16*   embf16= (f16*)(base + off);   off = align_up(off + (size_t)NE * CD * 2);
    f16*   zcf16 = (f16*)(base + off);   off = align_up(off + (size_t)MPAD * CD * 2);
    f16*   wet   = (f16*)(base + off);   off = align_up(off + (size_t)CIN * CD * 2);
    f16*   wchi  = (f16*)(base + off);   off = align_up(off + (size_t)CD * CIN * 2);
    f16*   wclo  = (f16*)(base + off);   off = align_up(off + (size_t)CD * CIN * 2);

    const size_t zsplit_bytes = (size_t)M_TOK * CIN * 2;
    bool have_split = (ws_size >= off + 2 * zsplit_bytes);
    f16 *zhi = nullptr, *zlo = nullptr;
    if (have_split) {
        zhi = (f16*)(base + off); off = align_up(off + zsplit_bytes);
        zlo = (f16*)(base + off); off = align_up(off + zsplit_bytes);
    }
    const size_t zc_bytes = (size_t)M_TOK * CD * 4;
    float* zc = (ws_size >= off + zc_bytes) ? (float*)(base + off) : out;

    if (have_split) {
        k_prep      <<<12272, 256, 0, stream>>>(emb, Wc, We, z, enorm, embf16,
                                                wchi, wclo, wet, zhi, zlo, loss_slot);
        k_compress_f<<<dim3(MPAD / 128, CD / 64), 256, 0, stream>>>(zhi, zlo, wchi, wclo,
                                                                    bc, zc, zcf16);
    } else {
        k_prep    <<<2816, 256, 0, stream>>>(emb, Wc, We, z, enorm, embf16,
                                             wchi, wclo, wet, (f16*)wchi, (f16*)wclo, loss_slot);
        k_compress<<<dim3(M_TOK / 64, CD / 64), 256, 0, stream>>>(z, Wc, bc, zc, zcf16);
    }

    k_dist_mfma  <<<dim3(MPAD / 128, NCHUNK), 256, 0, stream>>>(zcf16, embf16, enorm, part);
    k_rescore    <<<M_TOK / 4, 256, 0, stream>>>(zc, emb, enorm, part, idxp, loss_slot);
    k_expand_mfma<<<dim3(MPAD / 128, CIN / 128), 256, 0, stream>>>(embf16, idxp, wet, be, out);
}

// Round 6
// 277.156 us; speedup vs baseline: 1.1697x; 1.0289x over previous
//
#include <hip/hip_runtime.h>
#include <stdint.h>

// Problem constants (B=64, N=197)
#define M_TOK 12608      // 64*197 tokens
#define MPAD  12672      // 99 * 128
#define CIN   768
#define CD    256
#define NE    8192
#define NCHUNK 8
#define CHUNK  1024

typedef unsigned long long u64;
typedef unsigned int u32;
typedef _Float16 f16;
typedef _Float16 f16x8 __attribute__((ext_vector_type(8)));
typedef _Float16 f16x4 __attribute__((ext_vector_type(4)));
typedef float f32x4 __attribute__((ext_vector_type(4)));

#if __has_builtin(__builtin_amdgcn_global_load_lds)
#define HAVE_GLL 1
#else
#define HAVE_GLL 0
#endif

// Stage one 16B chunk per lane into LDS. lds_base is wave-uniform; HW (or the
// fallback) adds lane*16.
__device__ __forceinline__ void stage16(const f16* src, char* lds_base, int lane)
{
#if HAVE_GLL
    __builtin_amdgcn_global_load_lds(
        (__attribute__((address_space(1))) void*)(src),
        (__attribute__((address_space(3))) void*)(lds_base), 16, 0, 0);
#else
    *(f16x8*)(lds_base + lane * 16) = *(const f16x8*)src;
#endif
}

// ---------------------------------------------------------------------------
// Fused prep: region A (2048 blocks): enorm + embf16 + loss zero.
// Region B (768 blocks): weight prep (WcT hi/lo split, WeT f16).
// Region C (9456 blocks): z -> zhi + zlo split.
__global__ __launch_bounds__(256) void k_prep(const float* __restrict__ emb,
                                              const float* __restrict__ Wc,
                                              const float* __restrict__ We,
                                              const float* __restrict__ z,
                                              float* __restrict__ enorm,
                                              f16* __restrict__ embf16,
                                              f16* __restrict__ wchi,
                                              f16* __restrict__ wclo,
                                              f16* __restrict__ wet,
                                              f16* __restrict__ zhi,
                                              f16* __restrict__ zlo,
                                              float* __restrict__ loss_slot)
{
    const int b = blockIdx.x;
    const int t = threadIdx.x;
    if (b < 2048) {
        if (b == 0 && t == 0) *loss_slot = 0.0f;
        int row  = b * 4 + (t >> 6);
        int lane = t & 63;
        float4 v = *(const float4*)&emb[(size_t)row * CD + lane * 4];
        f16x4 hv = { (f16)v.x, (f16)v.y, (f16)v.z, (f16)v.w };
        *(f16x4*)&embf16[(size_t)row * CD + lane * 4] = hv;
        float s = v.x*v.x + v.y*v.y + v.z*v.z + v.w*v.w;
        #pragma unroll
        for (int o = 32; o; o >>= 1) s += __shfl_down(s, o, 64);
        if (lane == 0) enorm[row] = s;
    } else if (b < 2048 + 768) {
        int tid = (b - 2048) * 256 + t;            // < 196608
        {
            int n = tid & 255, k = tid >> 8;
            float v = Wc[(size_t)k * CD + n];
            f16 h = (f16)v;
            wchi[(size_t)n * CIN + k] = h;
            wclo[(size_t)n * CIN + k] = (f16)(v - (float)h);
        }
        {
            int d = tid / CIN, c = tid - d * CIN;
            wet[(size_t)c * CD + d] = (f16)We[(size_t)d * CIN + c];
        }
    } else {
        size_t i4 = (size_t)(b - 2816) * 256 + t;  // float4 idx, 2420736 total
        float4 v = ((const float4*)z)[i4];
        f16x4 h = { (f16)v.x, (f16)v.y, (f16)v.z, (f16)v.w };
        f16x4 lo = { (f16)(v.x - (float)h.x), (f16)(v.y - (float)h.y),
                     (f16)(v.z - (float)h.z), (f16)(v.w - (float)h.w) };
        ((f16x4*)zhi)[i4] = h;
        ((f16x4*)zlo)[i4] = lo;
    }
}

// ---------------------------------------------------------------------------
// Fused split-f16 compress: zc = zhi@WhiT + zhi@WloT + zlo@WhiT + bc, writes
// zc (f32) and zcf16. 128x64 tile, BK=64, K=768.
__global__ __launch_bounds__(256) void k_compress_f(const f16* __restrict__ zhi,
                                                    const f16* __restrict__ zlo,
                                                    const f16* __restrict__ wchi,
                                                    const f16* __restrict__ wclo,
                                                    const float* __restrict__ bc,
                                                    float* __restrict__ zc,
                                                    f16* __restrict__ zcf16)
{
    __shared__ __align__(16) f16 Ah[128 * 64];   // 16 KB
    __shared__ __align__(16) f16 Al[128 * 64];   // 16 KB
    __shared__ __align__(16) f16 Bh[64 * 64];    // 8 KB
    __shared__ __align__(16) f16 Bl[64 * 64];    // 8 KB

    const int t = threadIdx.x;
    const int w = t >> 6, l = t & 63;
    const int wrow = w * 32;
    const int m0   = blockIdx.x * 128;
    const int col0 = blockIdx.y * 64;

    const int cg   = (t & 7) ^ ((t >> 3) & 7);
    const int rloc = t >> 3;
    const f16* ahsrc[4]; const f16* alsrc[4];
    #pragma unroll
    for (int i = 0; i < 4; ++i) {
        int am = m0 + i * 32 + rloc; am = am < M_TOK ? am : (M_TOK - 1);
        ahsrc[i] = zhi + (size_t)am * CIN + cg * 8;
        alsrc[i] = zlo + (size_t)am * CIN + cg * 8;
    }
    const f16* bhsrc[2]; const f16* blsrc[2];
    #pragma unroll
    for (int i = 0; i < 2; ++i) {
        int br = col0 + i * 32 + rloc;
        bhsrc[i] = wchi + (size_t)br * CIN + cg * 8;
        blsrc[i] = wclo + (size_t)br * CIN + cg * 8;
    }

    f32x4 acc[2][4];
    #pragma unroll
    for (int a = 0; a < 2; ++a)
        #pragma unroll
        for (int b2 = 0; b2 < 4; ++b2) acc[a][b2] = (f32x4){0.f,0.f,0.f,0.f};

    for (int ks = 0; ks < CIN / 64; ++ks) {
        __syncthreads();
        #pragma unroll
        for (int i = 0; i < 4; ++i) {
            stage16(ahsrc[i] + ks * 64, (char*)Ah + (i * 256 + w * 64) * 16, l);
            stage16(alsrc[i] + ks * 64, (char*)Al + (i * 256 + w * 64) * 16, l);
        }
        #pragma unroll
        for (int i = 0; i < 2; ++i) {
            stage16(bhsrc[i] + ks * 64, (char*)Bh + (i * 256 + w * 64) * 16, l);
            stage16(blsrc[i] + ks * 64, (char*)Bl + (i * 256 + w * 64) * 16, l);
        }
        __syncthreads();
        #pragma unroll
        for (int kk = 0; kk < 2; ++kk) {
            const int pofs = ((kk * 4 + (l >> 4)) ^ (l & 7)) * 16;
            f16x8 ah[2], al[2], bh[4], bl[4];
            #pragma unroll
            for (int tm = 0; tm < 2; ++tm) {
                ah[tm] = *(const f16x8*)((const char*)Ah + (wrow + tm*16 + (l & 15)) * 128 + pofs);
                al[tm] = *(const f16x8*)((const char*)Al + (wrow + tm*16 + (l & 15)) * 128 + pofs);
            }
            #pragma unroll
            for (int tn = 0; tn < 4; ++tn) {
                bh[tn] = *(const f16x8*)((const char*)Bh + (tn*16 + (l & 15)) * 128 + pofs);
                bl[tn] = *(const f16x8*)((const char*)Bl + (tn*16 + (l & 15)) * 128 + pofs);
            }
            #pragma unroll
            for (int tm = 0; tm < 2; ++tm)
                #pragma unroll
                for (int tn = 0; tn < 4; ++tn) {
                    f32x4 a = acc[tm][tn];
                    a = __builtin_amdgcn_mfma_f32_16x16x32_f16(ah[tm], bh[tn], a, 0, 0, 0);
                    a = __builtin_amdgcn_mfma_f32_16x16x32_f16(ah[tm], bl[tn], a, 0, 0, 0);
                    a = __builtin_amdgcn_mfma_f32_16x16x32_f16(al[tm], bh[tn], a, 0, 0, 0);
                    acc[tm][tn] = a;
                }
        }
    }

    #pragma unroll
    for (int tm = 0; tm < 2; ++tm) {
        #pragma unroll
        for (int reg = 0; reg < 4; ++reg) {
            int row = m0 + wrow + tm * 16 + (l >> 4) * 4 + reg;
            if (row < M_TOK) {
                #pragma unroll
                for (int tn = 0; tn < 4; ++tn) {
                    int col = col0 + tn * 16 + (l & 15);
                    float v = acc[tm][tn][reg] + bc[col];
                    zc[(size_t)row * CD + col] = v;
                    zcf16[(size_t)row * CD + col] = (f16)v;
                }
            }
        }
    }
}

// ---------------------------------------------------------------------------
// Coarse distance GEMM v4: A (zc) bounced global->LDS->VGPRs (the LDS buffer
// is then overwritten by B tiles, so the compiler CANNOT rematerialize the A
// loads -- forces true register residency of afr[4][8] = 128 VGPRs/lane).
// LDS carries only B (32 KB per 64-col j-tile, XOR-swizzled).
__global__ __launch_bounds__(256, 2) void k_dist_mfma(const f16* __restrict__ zcf16,
                                                      const f16* __restrict__ embf16,
                                                      const float* __restrict__ enorm,
                                                      u64* __restrict__ part)
{
    __shared__ __align__(16) f16 Bs[64 * 256];   // 32 KB, swizzled rows of 512B
    __shared__ u64 wred[128][2][2];              // 4 KB

    const int t = threadIdx.x;
    const int w = t >> 6, l = t & 63;
    const int rg  = w >> 1;          // row-group (64 rows each)
    const int cgp = w & 1;           // col-group (32 of 64 cols per tile)
    const int m0    = blockIdx.x * 128;
    const int chunk = blockIdx.y;
    const int jbase = chunk * CHUNK;

    // ---- A fragments: 64 rows x 256 K in registers, bounced through LDS.
    f16x8 afr[4][8];
    #pragma unroll
    for (int h = 0; h < 2; ++h) {
        __syncthreads();
        #pragma unroll
        for (int i = 0; i < 8; ++i) {
            int r = (w * 8 + i) * 2 + (l >> 5);       // 0..63 within half
            int c = (l & 31) ^ (r & 7);
            int gr = m0 + h * 64 + r; gr = gr < M_TOK ? gr : (M_TOK - 1);
            stage16(zcf16 + (size_t)gr * CD + c * 8, (char*)Bs + (w * 8 + i) * 1024, l);
        }
        __syncthreads();
        if (rg == h) {
            #pragma unroll
            for (int mb = 0; mb < 4; ++mb) {
                int rl = mb * 16 + (l & 15);
                #pragma unroll
                for (int ks = 0; ks < 8; ++ks) {
                    int pc = (ks * 4 + (l >> 4)) ^ (rl & 7);
                    afr[mb][ks] = *(const f16x8*)((const char*)Bs + rl * 512 + pc * 16);
                }
            }
        }
    }

    float bd[2][16];
    #pragma unroll
    for (int sc = 0; sc < 2; ++sc)
        #pragma unroll
        for (int s = 0; s < 16; ++s) bd[sc][s] = __builtin_inff();

    for (int jt = 0; jt < 16; ++jt) {
        const int j0 = jbase + jt * 64;
        __syncthreads();
        // stage B tile: 64 cols x 256 K, chunk c of col r stored at slot c^(r&7)
        #pragma unroll
        for (int i = 0; i < 8; ++i) {
            int r = (w * 8 + i) * 2 + (l >> 5);
            int c = (l & 31) ^ (r & 7);
            stage16(embf16 + (size_t)(j0 + r) * CD + c * 8,
                    (char*)Bs + (w * 8 + i) * 1024, l);
        }
        __syncthreads();

        #pragma unroll
        for (int sc = 0; sc < 2; ++sc) {
            const int colrow = cgp * 32 + sc * 16 + (l & 15);
            f32x4 acc[4];
            #pragma unroll
            for (int mb = 0; mb < 4; ++mb) acc[mb] = (f32x4){0.f,0.f,0.f,0.f};
            #pragma unroll
            for (int ks = 0; ks < 8; ++ks) {
                int pc = (ks * 4 + (l >> 4)) ^ (colrow & 7);
                f16x8 bf = *(const f16x8*)((const char*)Bs + colrow * 512 + pc * 16);
                #pragma unroll
                for (int mb = 0; mb < 4; ++mb)
                    acc[mb] = __builtin_amdgcn_mfma_f32_16x16x32_f16(afr[mb][ks], bf, acc[mb], 0, 0, 0);
            }
            float en = enorm[j0 + colrow];
            #pragma unroll
            for (int mb = 0; mb < 4; ++mb) {
                #pragma unroll
                for (int reg = 0; reg < 4; ++reg) {
                    float d = fmaf(acc[mb][reg], -2.f, en);
                    float ds = __uint_as_float((__float_as_uint(d) & ~15u) | (u32)jt);
                    float cur = bd[sc][mb * 4 + reg];
                    bd[sc][mb * 4 + reg] = ds < cur ? ds : cur;
                }
            }
        }
    }

    // ---- per-row top-2 across the 16 col-lanes, then merge col-groups in LDS
    #pragma unroll
    for (int mb = 0; mb < 4; ++mb) {
        #pragma unroll
        for (int reg = 0; reg < 4; ++reg) {
            u64 key[2];
            #pragma unroll
            for (int sc = 0; sc < 2; ++sc) {
                u32 bits = __float_as_uint(bd[sc][mb * 4 + reg]);
                int jtb  = (int)(bits & 15u);
                int col  = jbase + jtb * 64 + cgp * 32 + sc * 16 + (l & 15);
                u32 u = (bits & 0x80000000u) ? ~bits : (bits | 0x80000000u);
                key[sc] = ((u64)u << 32) | (u32)col;
            }
            u64 b  = key[0] < key[1] ? key[0] : key[1];
            u64 s2 = key[0] < key[1] ? key[1] : key[0];
            #pragma unroll
            for (int off = 1; off <= 8; off <<= 1) {
                u64 ob = __shfl_xor(b, off, 64);
                u64 os = __shfl_xor(s2, off, 64);
                u64 nb = b < ob ? b : ob;
                u64 mx = b < ob ? ob : b;
                s2 = s2 < os ? s2 : os;
                s2 = s2 < mx ? s2 : mx;
                b = nb;
            }
            if ((l & 15) == 0) {
                int row = rg * 64 + mb * 16 + (l >> 4) * 4 + reg;
                wred[row][cgp][0] = b;
                wred[row][cgp][1] = s2;
            }
        }
    }
    __syncthreads();
    if (t < 128) {
        u64 b0 = wred[t][0][0], s0 = wred[t][0][1];
        u64 b1 = wred[t][1][0], s1 = wred[t][1][1];
        u64 B  = b0 < b1 ? b0 : b1;
        u64 mx = b0 < b1 ? b1 : b0;
        u64 S  = s0 < s1 ? s0 : s1;
        S = S < mx ? S : mx;
        int row = m0 + t;
        if (row < M_TOK) {
            part[((size_t)row * NCHUNK + chunk) * 2 + 0] = B;
            part[((size_t)row * NCHUNK + chunk) * 2 + 1] = S;
        }
    }
}

// ---------------------------------------------------------------------------
// Exact fp32 rescore: candidate = lane&15, K-quarter = lane>>4 (parallel dots,
// no serial candidate loop). Fused loss. One wave per row, 4 rows/block.
__global__ __launch_bounds__(256) void k_rescore(const float* __restrict__ zc,
                                                 const float* __restrict__ emb,
                                                 const float* __restrict__ enorm,
                                                 const u64* __restrict__ part,
                                                 int* __restrict__ idxp,
                                                 float* __restrict__ loss_slot)
{
    const int row = blockIdx.x * 4 + (threadIdx.x >> 6);   // grid 3152 -> exactly M_TOK
    const int l   = threadIdx.x & 63;
    const int c   = l & 15;       // candidate
    const int q   = l >> 4;       // K-quarter (64 elems)
    __shared__ float lsum[4];

    u64 key = part[(size_t)row * 16 + c];
    int col = (int)((u32)key & (NE - 1));
    const float4* ep = (const float4*)emb + (size_t)col * 64 + q * 16;
    const float4* zp = (const float4*)zc  + (size_t)row * 64 + q * 16;

    float p = 0.f, zn = 0.f;
    #pragma unroll
    for (int i = 0; i < 16; ++i) {
        float4 e = ep[i], zv = zp[i];
        p  = fmaf(e.x, zv.x, fmaf(e.y, zv.y, fmaf(e.z, zv.z, fmaf(e.w, zv.w, p))));
        zn = fmaf(zv.x, zv.x, fmaf(zv.y, zv.y, fmaf(zv.z, zv.z, fmaf(zv.w, zv.w, zn))));
    }
    p  += __shfl_xor(p, 16, 64);  p  += __shfl_xor(p, 32, 64);
    zn += __shfl_xor(zn, 16, 64); zn += __shfl_xor(zn, 32, 64);

    float d = fmaf(p, -2.f, enorm[col]);
    u32 u = __float_as_uint(d);
    u = (u & 0x80000000u) ? ~u : (u | 0x80000000u);
    u64 best = ((u64)u << 32) | (u32)col;
    #pragma unroll
    for (int off = 1; off <= 8; off <<= 1) {
        u64 ob = __shfl_xor(best, off, 64);
        best = ob < best ? ob : best;
    }

    u32 hi = (u32)(best >> 32);
    float dbest = (hi & 0x80000000u) ? __uint_as_float(hi & 0x7fffffffu)
                                     : __uint_as_float(~hi);
    if (l == 0) {
        idxp[row] = (int)((u32)best & (NE - 1));
        lsum[threadIdx.x >> 6] = dbest + zn;
    }
    __syncthreads();
    if (threadIdx.x == 0) {
        float tot = lsum[0] + lsum[1] + lsum[2] + lsum[3];
        atomicAdd(loss_slot, tot * (3.0f / 3227648.0f));
    }
}

// ---------------------------------------------------------------------------
// Expand GEMM (f16 MFMA, gathered A): out = embf16[idx] @ WeT^T + be. 128x128, K=256.
__global__ __launch_bounds__(256) void k_expand_mfma(const f16* __restrict__ embf16,
                                                     const int* __restrict__ idxp,
                                                     const f16* __restrict__ wet,
                                                     const float* __restrict__ be,
                                                     float* __restrict__ out)
{
    __shared__ __align__(16) f16 As[128 * 64];
    __shared__ __align__(16) f16 Bs[128 * 64];

    const int t = threadIdx.x;
    const int w = t >> 6, l = t & 63;
    const int wrow = (w >> 1) * 64, wcol = (w & 1) * 64;
    const int m0   = blockIdx.x * 128;
    const int col0 = blockIdx.y * 128;

    const int cg   = (t & 7) ^ ((t >> 3) & 7);
    const int rloc = t >> 3;
    const f16* asrc[4]; const f16* bsrc[4];
    #pragma unroll
    for (int i = 0; i < 4; ++i) {
        int r = i * 32 + rloc;
        int m = m0 + r; m = m < M_TOK ? m : (M_TOK - 1);
        int er = idxp[m];
        asrc[i] = embf16 + (size_t)er * CD + cg * 8;
        bsrc[i] = wet + (size_t)(col0 + r) * CD + cg * 8;
    }
    const int prd0 = (l >> 4) ^ (l & 7);
    const int prd1 = (4 + (l >> 4)) ^ (l & 7);

    f32x4 acc[4][4];
    #pragma unroll
    for (int a = 0; a < 4; ++a)
        #pragma unroll
        for (int b = 0; b < 4; ++b) acc[a][b] = (f32x4){0.f,0.f,0.f,0.f};

    for (int ks = 0; ks < 4; ++ks) {            // K = 256
        __syncthreads();
        #pragma unroll
        for (int i = 0; i < 4; ++i) {
            stage16(asrc[i] + ks * 64, (char*)As + (i * 256 + w * 64) * 16, l);
            stage16(bsrc[i] + ks * 64, (char*)Bs + (i * 256 + w * 64) * 16, l);
        }
        __syncthreads();
        #pragma unroll
        for (int kk = 0; kk < 2; ++kk) {
            const int pofs = (kk ? prd1 : prd0) * 16;
            f16x8 af[4], bf[4];
            #pragma unroll
            for (int tm = 0; tm < 4; ++tm)
                af[tm] = *(const f16x8*)((const char*)As + (wrow + tm*16 + (l & 15)) * 128 + pofs);
            #pragma unroll
            for (int tn = 0; tn < 4; ++tn)
                bf[tn] = *(const f16x8*)((const char*)Bs + (wcol + tn*16 + (l & 15)) * 128 + pofs);
            #pragma unroll
            for (int tm = 0; tm < 4; ++tm)
                #pragma unroll
                for (int tn = 0; tn < 4; ++tn)
                    acc[tm][tn] = __builtin_amdgcn_mfma_f32_16x16x32_f16(af[tm], bf[tn], acc[tm][tn], 0, 0, 0);
        }
    }

    float bev[4];
    #pragma unroll
    for (int tn = 0; tn < 4; ++tn) bev[tn] = be[col0 + wcol + tn * 16 + (l & 15)];
    #pragma unroll
    for (int tm = 0; tm < 4; ++tm) {
        #pragma unroll
        for (int reg = 0; reg < 4; ++reg) {
            int row = m0 + wrow + tm * 16 + (l >> 4) * 4 + reg;
            if (row < M_TOK) {
                #pragma unroll
                for (int tn = 0; tn < 4; ++tn) {
                    int col = col0 + wcol + tn * 16 + (l & 15);
                    out[(size_t)row * CIN + col] = acc[tm][tn][reg] + bev[tn];
                }
            }
        }
    }
}

// ---------------------------------------------------------------------------
// fp32 fallback compress (only if workspace too small for the split path)
#define BK1 16
__global__ __launch_bounds__(256) void k_compress(const float* __restrict__ z,
                                                  const float* __restrict__ W,
                                                  const float* __restrict__ bias,
                                                  float* __restrict__ zc,
                                                  f16* __restrict__ zcf16)
{
    __shared__ __align__(16) float As[BK1][64 + 4];
    __shared__ __align__(16) float Bs[BK1][64 + 4];
    const int t  = threadIdx.x;
    const int tx = t & 15, ty = t >> 4;
    const int row0 = blockIdx.x * 64;
    const int col0 = blockIdx.y * 64;

    const int la_r = t >> 2;
    const int la_k = (t & 3) << 2;
    const int lb_k = t >> 4;
    const int lb_n = (t & 15) << 2;

    float acc[4][4] = {};

    for (int k0 = 0; k0 < CIN; k0 += BK1) {
        float4 a4 = *(const float4*)&z[(size_t)(row0 + la_r) * CIN + k0 + la_k];
        float4 b4 = *(const float4*)&W[(size_t)(k0 + lb_k) * CD + col0 + lb_n];
        __syncthreads();
        As[la_k + 0][la_r] = a4.x; As[la_k + 1][la_r] = a4.y;
        As[la_k + 2][la_r] = a4.z; As[la_k + 3][la_r] = a4.w;
        *(float4*)&Bs[lb_k][lb_n] = b4;
        __syncthreads();
        #pragma unroll
        for (int k = 0; k < BK1; ++k) {
            float a[4], b[4];
            *(float4*)&a[0] = *(const float4*)&As[k][ty * 4];
            *(float4*)&b[0] = *(const float4*)&Bs[k][tx * 4];
            #pragma unroll
            for (int i = 0; i < 4; ++i)
                #pragma unroll
                for (int j = 0; j < 4; ++j)
                    acc[i][j] = fmaf(a[i], b[j], acc[i][j]);
        }
    }

    float4 bb = *(const float4*)&bias[col0 + tx * 4];
    #pragma unroll
    for (int i = 0; i < 4; ++i) {
        float4 v;
        v.x = acc[i][0] + bb.x; v.y = acc[i][1] + bb.y;
        v.z = acc[i][2] + bb.z; v.w = acc[i][3] + bb.w;
        size_t off = (size_t)(row0 + ty * 4 + i) * CD + col0 + tx * 4;
        *(float4*)&zc[off] = v;
        f16x4 hv = { (f16)v.x, (f16)v.y, (f16)v.z, (f16)v.w };
        *(f16x4*)&zcf16[off] = hv;
    }
}

// ---------------------------------------------------------------------------
extern "C" void kernel_launch(void* const* d_in, const int* in_sizes, int n_in,
                              void* d_out, int out_size, void* d_ws, size_t ws_size,
                              hipStream_t stream)
{
    (void)in_sizes; (void)n_in; (void)out_size;

    const float* z   = (const float*)d_in[0];
    const float* emb = (const float*)d_in[1];
    const float* Wc  = (const float*)d_in[2];
    const float* bc  = (const float*)d_in[3];
    const float* We  = (const float*)d_in[4];
    const float* be  = (const float*)d_in[5];

    float* out       = (float*)d_out;
    float* loss_slot = out + (size_t)M_TOK * CIN;

    char* base = (char*)d_ws;
    size_t off = 0;
    auto align_up = [](size_t x) { return (x + 255) & ~(size_t)255; };

    float* enorm = (float*)(base + off); off = align_up(off + (size_t)NE * 4);
    u64*   part  = (u64*)(base + off);   off = align_up(off + (size_t)M_TOK * 16 * 8);
    int*   idxp  = (int*)(base + off);   off = align_up(off + (size_t)M_TOK * 4);
    f16*   embf16= (f16*)(base + off);   off = align_up(off + (size_t)NE * CD * 2);
    f16*   zcf16 = (f16*)(base + off);   off = align_up(off + (size_t)MPAD * CD * 2);
    f16*   wet   = (f16*)(base + off);   off = align_up(off + (size_t)CIN * CD * 2);
    f16*   wchi  = (f16*)(base + off);   off = align_up(off + (size_t)CD * CIN * 2);
    f16*   wclo  = (f16*)(base + off);   off = align_up(off + (size_t)CD * CIN * 2);

    const size_t zsplit_bytes = (size_t)M_TOK * CIN * 2;
    bool have_split = (ws_size >= off + 2 * zsplit_bytes);
    f16 *zhi = nullptr, *zlo = nullptr;
    if (have_split) {
        zhi = (f16*)(base + off); off = align_up(off + zsplit_bytes);
        zlo = (f16*)(base + off); off = align_up(off + zsplit_bytes);
    }
    const size_t zc_bytes = (size_t)M_TOK * CD * 4;
    float* zc = (ws_size >= off + zc_bytes) ? (float*)(base + off) : out;

    if (have_split) {
        k_prep      <<<12272, 256, 0, stream>>>(emb, Wc, We, z, enorm, embf16,
                                                wchi, wclo, wet, zhi, zlo, loss_slot);
        k_compress_f<<<dim3(MPAD / 128, CD / 64), 256, 0, stream>>>(zhi, zlo, wchi, wclo,
                                                                    bc, zc, zcf16);
    } else {
        k_prep    <<<2816, 256, 0, stream>>>(emb, Wc, We, z, enorm, embf16,
                                             wchi, wclo, wet, (f16*)wchi, (f16*)wclo, loss_slot);
        k_compress<<<dim3(M_TOK / 64, CD / 64), 256, 0, stream>>>(z, Wc, bc, zc, zcf16);
    }

    k_dist_mfma  <<<dim3(MPAD / 128, NCHUNK), 256, 0, stream>>>(zcf16, embf16, enorm, part);
    k_rescore    <<<M_TOK / 4, 256, 0, stream>>>(zc, emb, enorm, part, idxp, loss_slot);
    k_expand_mfma<<<dim3(MPAD / 128, CIN / 128), 256, 0, stream>>>(embf16, idxp, wet, be, out);
}